// Round 13
// baseline (79.974 us; speedup 1.0000x reference)
//
#include <hip/hip_runtime.h>
#include <stdint.h>

#define N_ANCH 67200
#define KCAP   1000
#define CONF_THR 0.7f
#define NMS_THR  0.4f

// score-bits histogram: scores in (0.7, 1.0] -> bits in (0x3F333333, 0x3F800000]
// span = 0x4CCCCD ulp; shift 10 -> 4917 live buckets; NBUCK = 5120 = 1024*5.
#define BUCK_BASE 0x3F333333u
#define BUCK_SHIFT 10
#define NBUCK 5120
#define CAPG 4096             // bucket-sorted key capacity (kept ~ 1010)

#define FUS_BLKS 63           // 63*16 = 1008 rows >= KCAP; coop co-resident

// ---- workspace layout (bytes), ~801 KB total ----
#define OFF_CTR   0           // [0]=M, [1]=done_scatter, [2]=decode_flag, [3]=done_sup
#define OFF_HIST  64          // +NBUCK*4 = 20480 -> 20544
#define OFF_FILL  20544       // +20480 -> 41024
#define OFF_LIST  41024       // +N_ANCH*8 = 537600 -> 578624
#define OFF_GKEYS 578624      // +CAPG*8 = 32768 -> 611392
#define OFF_SCORE 611392      // +4096 -> 615488
#define OFF_BOX   615488      // +16384 -> 631872 (16B aligned)
#define OFF_LM    631872      // +40960 -> 672832
#define OFF_SUP   672832      // +128000 -> 800832

__device__ inline unsigned long long shfl_xor_u64(unsigned long long v, int m) {
    unsigned int lo = (unsigned int)__shfl_xor((int)(v & 0xffffffffull), m, 64);
    unsigned int hi = (unsigned int)__shfl_xor((int)(v >> 32), m, 64);
    return ((unsigned long long)hi << 32) | lo;
}

__device__ inline int bucket_of(unsigned int sb) {
    return min((int)((sb - BUCK_BASE) >> BUCK_SHIFT), NBUCK - 1);
}

// findcut (largest B with suffix-count >= KCAP, else 0; early-exits after the
// crossing chunk, ~5 iters in practice) + in-place suffix scan turning hist[]
// into sufx[] (descending segment starts). 1024 threads. readlane returns
// int -> widen through unsigned int (round-2 lesson).
__device__ inline void findcut_and_scan(int* sufx, int* swsum, int* sB,
                                        int tid, int lane, int wv) {
    if (tid < 64) {
        int acc = 0, B = 0;
        bool found = false;
        for (int t = 0; t < NBUCK / 64 && !found; ++t) {
            int base = NBUCK - 64 * (t + 1);
            int c = sufx[base + lane];
            int ssum = c;
#pragma unroll
            for (int off = 1; off < 64; off <<= 1)
                ssum += __shfl_xor(ssum, off, 64);
            if (acc + ssum >= KCAP) {
                for (int l = 63; l >= 0; --l) {
                    int cl = (int)__builtin_amdgcn_readlane((unsigned int)c, l);
                    if (acc + cl >= KCAP) { B = base + l; found = true; break; }
                    acc += cl;
                }
            } else {
                acc += ssum;
            }
        }
        if (lane == 0) *sB = found ? B : 0;
    }
    __syncthreads();
    int c[5];
#pragma unroll
    for (int k = 0; k < 5; ++k)
        c[k] = sufx[NBUCK - 1 - (tid * 5 + k)];
    int tsum = c[0] + c[1] + c[2] + c[3] + c[4];
    int inc = tsum;
#pragma unroll
    for (int off = 1; off < 64; off <<= 1) {
        int n = __shfl_up(inc, off, 64);
        if (lane >= off) inc += n;
    }
    if (lane == 63) swsum[wv] = inc;
    __syncthreads();
    if (tid < 16) {
        int v = swsum[tid];
        int s = v;
#pragma unroll
        for (int off = 1; off < 16; off <<= 1) {
            int n = __shfl_up(s, off, 64);
            if (tid >= off) s += n;
        }
        swsum[tid] = s - v;  // exclusive wave base
    }
    __syncthreads();
    int run = swsum[wv] + inc - tsum;  // exclusive prefix (reversed order)
#pragma unroll
    for (int k = 0; k < 5; ++k) {
        sufx[NBUCK - 1 - (tid * 5 + k)] = run;
        run += c[k];
    }
    __syncthreads();
}

// K0: zero counters + histogram + fill (rocclr fill is pathological: 40us).
__global__ __launch_bounds__(1024) void k_zero(int* __restrict__ ctr,
                                               int* __restrict__ hist,
                                               int* __restrict__ gfill) {
    int tid = threadIdx.x;
    if (tid < 16) ctr[tid] = 0;
    for (int t = tid; t < NBUCK; t += 1024) { hist[t] = 0; gfill[t] = 0; }
}

// K1: softmax, threshold, wave-aggregated dense compact + histogram.
// key = (score_bits<<32) | (0xFFFFFFFF - index): descending key order ==
// lax.top_k order (ties -> ascending index). List order nondeterministic;
// exact ranking downstream keeps outputs deterministic.
__global__ __launch_bounds__(256) void k_front(const float* __restrict__ conf,
                                               unsigned long long* __restrict__ list,
                                               int* __restrict__ hist,
                                               int* __restrict__ ctr) {
    int t = blockIdx.x * 256 + threadIdx.x;   // float4 index = 2 anchors
    int lane = threadIdx.x & 63;
    int a0 = t * 2;
    bool p0 = false, p1 = false;
    unsigned long long k0 = 0ull, k1 = 0ull;
    if (a0 < N_ANCH) {
        float4 c = reinterpret_cast<const float4*>(conf)[t];
        {
            float mx = fmaxf(c.x, c.y);
            float e0 = expf(c.x - mx), e1 = expf(c.y - mx);
            float s = e1 / (e0 + e1);
            if (s > CONF_THR) {
                p0 = true;
                k0 = ((unsigned long long)__float_as_uint(s) << 32)
                   | (unsigned int)(0xFFFFFFFFu - (unsigned int)a0);
            }
        }
        {
            float mx = fmaxf(c.z, c.w);
            float e0 = expf(c.z - mx), e1 = expf(c.w - mx);
            float s = e1 / (e0 + e1);
            if (s > CONF_THR) {
                p1 = true;
                k1 = ((unsigned long long)__float_as_uint(s) << 32)
                   | (unsigned int)(0xFFFFFFFFu - (unsigned int)(a0 + 1));
            }
        }
    }
    unsigned long long m0 = __ballot(p0);
    unsigned long long m1 = __ballot(p1);
    int n0 = (int)__popcll(m0), n1 = (int)__popcll(m1);
    int base = 0;
    if ((n0 + n1) > 0) {
        if (lane == 0) base = atomicAdd(&ctr[0], n0 + n1);
        base = __shfl(base, 0, 64);
        unsigned long long below = (1ull << lane) - 1ull;
        if (p0) {
            list[base + (int)__popcll(m0 & below)] = k0;
            atomicAdd(&hist[bucket_of((unsigned int)(k0 >> 32))], 1);
        }
        if (p1) {
            list[base + n0 + (int)__popcll(m1 & below)] = k1;
            atomicAdd(&hist[bucket_of((unsigned int)(k1 >> 32))], 1);
        }
    }
}

// K2 (cooperative, FUS_BLKS blocks x 1024): scatter -> (last block) rank +
// decode -> flag -> sup rows -> (last block) sparse scan + output.
// All cross-block handoffs use the proven release/acquire done-counter
// pattern (threadfence + device-scope atomics, validated r11/r12). The
// decode->sup handoff is a spin-flag: deadlock-free because cooperative
// launch guarantees all FUS_BLKS blocks are co-resident; only thread 0 of
// each block polls (s_sleep backoff), the rest wait at __syncthreads.
__global__ __launch_bounds__(1024) void k_fused(
        const unsigned long long* __restrict__ list,
        const int* __restrict__ hist,
        int* __restrict__ gfill,
        unsigned long long* __restrict__ gkeys,
        int* __restrict__ ctr,
        const float* __restrict__ loc,
        const float* __restrict__ land,
        const float* __restrict__ priors,
        float* __restrict__ sel_score,
        float* __restrict__ sel_box,
        float* __restrict__ sel_lm,
        unsigned long long* __restrict__ sup,
        float* __restrict__ out) {
#pragma clang fp contract(off)
    __shared__ union {
        int sufx[NBUCK];                      // scatter/decode phases (20 KB)
        unsigned long long sup_r[1024][16];   // scan phase (128 KB)
    } u;
    __shared__ int swsum[16];
    __shared__ int sB;
    __shared__ int slast;
    __shared__ unsigned long long mshare[16];
    __shared__ unsigned long long keep_final[16];
    int tid = threadIdx.x, lane = tid & 63, wave = tid >> 6;
    int bid = blockIdx.x;
    int M = min(ctr[0], N_ANCH);
    int V = min(M, KCAP);

    // ---- phase A: per-block findcut + sufx, scatter slice into gkeys ----
    for (int t = tid; t < NBUCK; t += 1024) u.sufx[t] = hist[t];
    __syncthreads();
    findcut_and_scan(u.sufx, swsum, &sB, tid, lane, wave);
    int B = sB;
    for (int p = bid * 1024 + tid; p < M; p += FUS_BLKS * 1024) {
        unsigned long long k = list[p];
        int b = bucket_of((unsigned int)(k >> 32));
        if (b >= B) {
            int off = atomicAdd(&gfill[b], 1);
            int slot = u.sufx[b] + off;
            if (slot < CAPG) gkeys[slot] = k;
        }
    }
    __syncthreads();
    if (tid == 0) {
        __threadfence();                       // release scatter
        int old = atomicAdd(&ctr[1], 1);
        slast = (old == FUS_BLKS - 1);
    }
    __syncthreads();

    int S = min((B > 0) ? u.sufx[B - 1] : M, CAPG);

    // ---- phase B (last scatter block): exact rank + decode into slots ----
    if (slast) {
        if (tid == 0) __threadfence();         // acquire
        __syncthreads();
        for (int s = tid; s < S; s += 1024) {
            unsigned long long key = gkeys[s];
            unsigned int sb = (unsigned int)(key >> 32);
            int b = bucket_of(sb);
            int seg0 = u.sufx[b];
            int segn = gfill[b];
            int within = 0;
            for (int t = 0; t < segn && seg0 + t < CAPG; ++t)
                within += (gkeys[seg0 + t] > key) ? 1 : 0;
            int r = seg0 + within;
            if (r < KCAP) {
                unsigned int a = 0xFFFFFFFFu - (unsigned int)(key & 0xFFFFFFFFull);
                sel_score[r] = __uint_as_float(sb);
                float pcx = priors[a*4+0], pcy = priors[a*4+1];
                float pw  = priors[a*4+2], ph  = priors[a*4+3];
                float l0 = loc[a*4+0], l1 = loc[a*4+1], l2 = loc[a*4+2], l3 = loc[a*4+3];
                // replicate reference op order exactly:
                float cx = pcx + (l0 * 0.1f) * pw;
                float cy = pcy + (l1 * 0.1f) * ph;
                float w  = pw * expf(l2 * 0.2f);
                float h2 = ph * expf(l3 * 0.2f);
                float x1 = cx - w * 0.5f;
                float y1 = cy - h2 * 0.5f;
                sel_box[r*4+0] = x1 * 1280.0f;
                sel_box[r*4+1] = y1 * 1280.0f;
                sel_box[r*4+2] = (x1 + w) * 1280.0f;
                sel_box[r*4+3] = (y1 + h2) * 1280.0f;
#pragma unroll
                for (int q = 0; q < 5; ++q) {
                    float lx = land[a*10 + 2*q + 0];
                    float ly = land[a*10 + 2*q + 1];
                    sel_lm[r*10 + 2*q + 0] = (pcx + (lx * 0.1f) * pw) * 1280.0f;
                    sel_lm[r*10 + 2*q + 1] = (pcy + (ly * 0.1f) * ph) * 1280.0f;
                }
            }
        }
        __syncthreads();
        if (tid == 0) {
            __threadfence();                   // release decode
            atomicExch(&ctr[2], 1);            // decode-done flag
        }
    }

    // ---- all blocks: wait for decode flag (spin, co-residency guaranteed) --
    if (tid == 0) {
        while (atomicAdd(&ctr[2], 0) == 0)
            __builtin_amdgcn_s_sleep(8);
        __threadfence();                       // acquire sel_*
    }
    __syncthreads();

    // ---- phase C: suppression rows (wave handles row i) ----
    {
        int i = bid * 16 + wave;               // 0..1007
        if (i < KCAP) {
            bool irow = (i < V);
            float ax1 = 0.f, ay1 = 0.f, ax2 = 0.f, ay2 = 0.f, aarea = 0.f;
            if (irow) {
                ax1 = sel_box[i*4+0]; ay1 = sel_box[i*4+1];
                ax2 = sel_box[i*4+2]; ay2 = sel_box[i*4+3];
                aarea = (ax2 - ax1) * (ay2 - ay1);
            }
            for (int g = 0; g < 16; ++g) {
                int j = g * 64 + lane;
                bool pred = false;
                if (irow && j < V && j > i) {
                    float4 b = reinterpret_cast<const float4*>(sel_box)[j];
                    float barea = (b.z - b.x) * (b.w - b.y);
                    float ltx = fmaxf(ax1, b.x), lty = fmaxf(ay1, b.y);
                    float rbx = fminf(ax2, b.z), rby = fminf(ay2, b.w);
                    float wx = fmaxf(rbx - ltx, 0.0f);
                    float wy = fmaxf(rby - lty, 0.0f);
                    float inter = wx * wy;
                    float iou = inter / (aarea + barea - inter + 1e-12f);
                    pred = iou > NMS_THR;
                }
                unsigned long long mask = __ballot(pred);
                if (lane == 0) sup[i*16 + g] = mask;
            }
        }
    }
    __syncthreads();
    if (tid == 0) {
        __threadfence();                       // release sup
        int old = atomicAdd(&ctr[3], 1);
        slast = (old == FUS_BLKS - 1);
    }
    __syncthreads();
    if (!slast) return;
    if (tid == 0) __threadfence();             // acquire
    __syncthreads();

    // ---- phase D (last sup block): sparse greedy scan + output write ----
    {   // stage sup via 16B loads (8000 ulonglong2)
        const ulonglong2* sup2 = reinterpret_cast<const ulonglong2*>(sup);
        for (int idx = tid; idx < KCAP * 8; idx += 1024) {
            ulonglong2 v = sup2[idx];
            int e0 = idx * 2;
            int r = e0 >> 4, w0 = e0 & 15;
            u.sup_r[r][w0 ^ (r & 15)] = v.x;
            u.sup_r[r][(w0 + 1) ^ (r & 15)] = v.y;
        }
    }
    if (tid < 24 * 16) { // zero rows 1000..1023
        int r = 1000 + (tid >> 4), w = tid & 15;
        u.sup_r[r][w ^ (r & 15)] = 0ull;
    }
    unsigned long long kw;
    {
        int lo = wave * 64;
        kw = (V >= lo + 64) ? ~0ull : (V <= lo ? 0ull : ((1ull << (V - lo)) - 1ull));
    }
    __syncthreads();

    for (int c = 0; c < 16; ++c) {
        if (wave == c) {
            unsigned long long drow = u.sup_r[c*64 + lane][c ^ (lane & 15)];
            unsigned int dlo = (unsigned int)drow;
            unsigned int dhi = (unsigned int)(drow >> 32);
            unsigned long long nz = __ballot(drow != 0ull);
            unsigned long long m = kw;
            unsigned long long todo = m & nz;
            while (todo) {
                int i = (int)__builtin_ctzll(todo);
                i = __builtin_amdgcn_readfirstlane(i);
                unsigned long long di =
                    (((unsigned long long)(unsigned int)__builtin_amdgcn_readlane(dhi, i)) << 32)
                  |  (unsigned long long)(unsigned int)__builtin_amdgcn_readlane(dlo, i);
                m &= ~di;            // di only holds j>i bits
                todo &= ~di;         // suppressed rows never processed
                todo &= todo - 1ull; // clear bit i
            }
            kw = m;
            if (lane == 0) mshare[c] = m;
        }
        __syncthreads();
        if (wave > c) {
            unsigned long long m = mshare[c];
            unsigned long long contrib = ((m >> lane) & 1ull)
                ? u.sup_r[c*64 + lane][wave ^ (lane & 15)] : 0ull;
            if (__ballot(contrib != 0ull) != 0ull) {
#pragma unroll
                for (int off = 1; off < 64; off <<= 1)
                    contrib |= shfl_xor_u64(contrib, off);
                kw &= ~contrib;
            }
        }
    }
    if (lane == 0) keep_final[wave] = kw;
    __syncthreads();

    // outputs: boxes [0,4000), scores [4000,5000), landms [5000,15000)
    for (int s = tid; s < KCAP; s += 1024) {
        bool kept = ((keep_final[s >> 6] >> (s & 63)) & 1ull) != 0ull;
        float4 b = make_float4(0.f, 0.f, 0.f, 0.f);
        float sc = 0.f;
        if (kept) {
            b  = reinterpret_cast<const float4*>(sel_box)[s];
            sc = sel_score[s];
        }
        reinterpret_cast<float4*>(out)[s] = b;
        out[4000 + s] = sc;
#pragma unroll
        for (int q = 0; q < 10; ++q)
            out[5000 + s*10 + q] = kept ? sel_lm[s*10 + q] : 0.f;
    }
}

extern "C" void kernel_launch(void* const* d_in, const int* in_sizes, int n_in,
                              void* d_out, int out_size, void* d_ws, size_t ws_size,
                              hipStream_t stream) {
    const float* loc    = (const float*)d_in[0];
    const float* conf   = (const float*)d_in[1];
    const float* land   = (const float*)d_in[2];
    const float* priors = (const float*)d_in[3];
    float* out = (float*)d_out;
    char* ws = (char*)d_ws;

    int* ctr                     = (int*)(ws + OFF_CTR);
    int* hist                    = (int*)(ws + OFF_HIST);
    int* gfill                   = (int*)(ws + OFF_FILL);
    unsigned long long* list     = (unsigned long long*)(ws + OFF_LIST);
    unsigned long long* gkeys    = (unsigned long long*)(ws + OFF_GKEYS);
    float* sel_score             = (float*)(ws + OFF_SCORE);
    float* sel_box               = (float*)(ws + OFF_BOX);
    float* sel_lm                = (float*)(ws + OFF_LM);
    unsigned long long* sup      = (unsigned long long*)(ws + OFF_SUP);

    int nfb = (N_ANCH / 2 + 255) / 256; // 132
    k_zero<<<1, 1024, 0, stream>>>(ctr, hist, gfill);
    k_front<<<nfb, 256, 0, stream>>>(conf, list, hist, ctr);

    void* args[] = { (void*)&list, (void*)&hist, (void*)&gfill, (void*)&gkeys,
                     (void*)&ctr, (void*)&loc, (void*)&land, (void*)&priors,
                     (void*)&sel_score, (void*)&sel_box, (void*)&sel_lm,
                     (void*)&sup, (void*)&out };
    hipLaunchCooperativeKernel((const void*)k_fused, dim3(FUS_BLKS), dim3(1024),
                               args, 0, stream);
}

// Round 14
// 67.995 us; speedup vs baseline: 1.1762x; 1.1762x over previous
//
#include <hip/hip_runtime.h>
#include <stdint.h>

#define N_ANCH 67200
#define KCAP   1000
#define CONF_THR 0.7f
#define NMS_THR  0.4f

// coarse score-bits histogram: scores in (0.7, 1.0] -> bits span 0x4CCCCD ulp;
// shift 15 -> 154 live buckets; NBUCKC = 192 = 3*64. Avg occupancy ~120 keys,
// so within-bucket exact rank is ~120 L1-hot compares.
#define BUCK_BASE 0x3F333333u
#define CSHIFT 15
#define NBUCKC 192
#define CAPG 4096             // bucket-sorted key capacity (kept ~ 1120)

#define NFB 132               // front blocks; each owns a 512-anchor segment
#define MID_BLKS 32
#define SUP_BLKS 63           // 63*16 = 1008 rows >= KCAP

// ---- workspace layout (bytes), ~846 KB ----
#define OFF_CTR   0           // [0]=V, [1]=done_mid, [2]=done_sup
#define OFF_BCNT  64          // +132*4 = 528 -> 640 (padded)
#define OFF_BHIST 640         // +132*192*4 = 101376 -> 102016
#define OFF_FILL  102016      // +192*4 = 768 -> 102784
#define OFF_LIST  102784      // +132*512*8 = 540672 -> 643456
#define OFF_GKEYS 643456      // +CAPG*8 = 32768 -> 676224
#define OFF_SCORE 676224      // +4096 -> 680320
#define OFF_BOX   680320      // +16384 -> 696704 (16B aligned)
#define OFF_LM    696704      // +40960 -> 737664
#define OFF_SUP   737664      // +128000 -> 865664

__device__ inline unsigned long long shfl_xor_u64(unsigned long long v, int m) {
    unsigned int lo = (unsigned int)__shfl_xor((int)(v & 0xffffffffull), m, 64);
    unsigned int hi = (unsigned int)__shfl_xor((int)(v >> 32), m, 64);
    return ((unsigned long long)hi << 32) | lo;
}

__device__ inline int bucket_of(unsigned int sb) {
    return min((int)((sb - BUCK_BASE) >> CSHIFT), NBUCKC - 1);
}

// K1: block-local front end. Block owns anchors [blk*512, blk*512+512):
// softmax, threshold, compact into list[blk*512 + pos] (LDS counter), build
// LDS 192-bucket histogram, then write bhist[blk][*] (fully written -> no
// pre-zeroing anywhere) and bcnt[blk]. Block 0 zeroes gfill + done counters
// (untouched until next dispatch -> race-free). key = (score_bits<<32) |
// (0xFFFFFFFF - index): descending key order == lax.top_k order.
__global__ __launch_bounds__(256) void k_front(const float* __restrict__ conf,
                                               unsigned long long* __restrict__ list,
                                               int* __restrict__ bhist,
                                               int* __restrict__ bcnt,
                                               int* __restrict__ gfill,
                                               int* __restrict__ ctr) {
    __shared__ int lhist[NBUCKC];
    __shared__ int lcnt;
    int tid = threadIdx.x, lane = tid & 63;
    int blk = blockIdx.x;
    if (tid < NBUCKC) lhist[tid] = 0;
    if (tid == 0) lcnt = 0;
    __syncthreads();

    int p = blk * 256 + tid;              // float4 index = 2 anchors
    int a0 = p * 2;
    bool p0 = false, p1 = false;
    unsigned long long k0 = 0ull, k1 = 0ull;
    if (a0 < N_ANCH) {
        float4 c = reinterpret_cast<const float4*>(conf)[p];
        {
            float mx = fmaxf(c.x, c.y);
            float e0 = expf(c.x - mx), e1 = expf(c.y - mx);
            float s = e1 / (e0 + e1);
            if (s > CONF_THR) {
                p0 = true;
                k0 = ((unsigned long long)__float_as_uint(s) << 32)
                   | (unsigned int)(0xFFFFFFFFu - (unsigned int)a0);
            }
        }
        {
            float mx = fmaxf(c.z, c.w);
            float e0 = expf(c.z - mx), e1 = expf(c.w - mx);
            float s = e1 / (e0 + e1);
            if (s > CONF_THR) {
                p1 = true;
                k1 = ((unsigned long long)__float_as_uint(s) << 32)
                   | (unsigned int)(0xFFFFFFFFu - (unsigned int)(a0 + 1));
            }
        }
    }
    unsigned long long m0 = __ballot(p0);
    unsigned long long m1 = __ballot(p1);
    int n0 = (int)__popcll(m0), n1 = (int)__popcll(m1);
    int base = 0;
    if (lane == 0 && (n0 + n1) > 0) base = atomicAdd(&lcnt, n0 + n1);
    base = __shfl(base, 0, 64);
    unsigned long long below = (1ull << lane) - 1ull;
    int gbase = blk * 512;
    if (p0) {
        list[gbase + base + (int)__popcll(m0 & below)] = k0;
        atomicAdd(&lhist[bucket_of((unsigned int)(k0 >> 32))], 1);
    }
    if (p1) {
        list[gbase + base + n0 + (int)__popcll(m1 & below)] = k1;
        atomicAdd(&lhist[bucket_of((unsigned int)(k1 >> 32))], 1);
    }
    __syncthreads();
    if (tid < NBUCKC) bhist[blk * NBUCKC + tid] = lhist[tid];
    if (tid == 0) bcnt[blk] = lcnt;
    if (blk == 0) {  // zero next-phase state (unused until next dispatch)
        if (tid < NBUCKC) gfill[tid] = 0;
        if (tid == 192) ctr[1] = 0;
        if (tid == 193) ctr[2] = 0;
    }
}

// K2: 32 blocks. Each: sum bhist -> 192-bucket hist, findcut (wave 0),
// suffix-scan (wave 0, 3 chunks), then scatter its share of list segments
// (predicated by bcnt) into bucket-sorted gkeys via global gfill atomics.
// Last block (release/acquire done-counter, validated r11/r12) does exact
// rank (segment start + within-bucket count) + decode into slots.
__global__ __launch_bounds__(1024) void k_midrank(
        const unsigned long long* __restrict__ list,
        const int* __restrict__ bhist,
        const int* __restrict__ bcnt,
        int* __restrict__ gfill,
        unsigned long long* __restrict__ gkeys,
        int* __restrict__ ctr,
        const float* __restrict__ loc,
        const float* __restrict__ land,
        const float* __restrict__ priors,
        float* __restrict__ sel_score,
        float* __restrict__ sel_box,
        float* __restrict__ sel_lm) {
#pragma clang fp contract(off)
    __shared__ int chist[NBUCKC];   // counts, then in-place sufx
    __shared__ int scnt[NFB];
    __shared__ int sB, sM;
    __shared__ int slast;
    int tid = threadIdx.x, lane = tid & 63;
    int bid = blockIdx.x;

    if (tid < NFB) scnt[tid] = bcnt[tid];
    if (tid < NBUCKC) {            // sum per-block histograms (L2-hot, 101 KB)
        int s = 0;
#pragma unroll 4
        for (int j = 0; j < NFB; ++j) s += bhist[j * NBUCKC + tid];
        chist[tid] = s;
    }
    __syncthreads();

    // findcut (wave 0): largest B with suffix-count >= KCAP, else 0.
    // readlane returns int -> widen through unsigned int (round-2 lesson).
    if (tid < 64) {
        int acc = 0, B = 0;
        bool found = false;
        for (int t = 0; t < NBUCKC / 64 && !found; ++t) {
            int base = NBUCKC - 64 * (t + 1);
            int c = chist[base + lane];
            int ssum = c;
#pragma unroll
            for (int off = 1; off < 64; off <<= 1)
                ssum += __shfl_xor(ssum, off, 64);
            if (acc + ssum >= KCAP) {
                for (int l = 63; l >= 0; --l) {
                    int cl = (int)__builtin_amdgcn_readlane((unsigned int)c, l);
                    if (acc + cl >= KCAP) { B = base + l; found = true; break; }
                    acc += cl;
                }
            } else {
                acc += ssum;
            }
        }
        if (lane == 0) sB = found ? B : 0;
    }
    __syncthreads();
    // suffix-scan in-place (wave 0): chist[b] <- #keys in buckets > b.
    if (tid < 64) {
        int acc = 0;
        for (int t = 0; t < NBUCKC / 64; ++t) {
            int base = NBUCKC - 64 * (t + 1);
            int c = chist[base + lane];
            int inc = c;                       // inclusive suffix within chunk
#pragma unroll
            for (int off = 1; off < 64; off <<= 1) {
                int n = __shfl_down(inc, off, 64);
                if (lane + off < 64) inc += n;
            }
            chist[base + lane] = acc + inc - c; // exclusive suffix
            acc += __shfl(inc, 0, 64);          // chunk total
        }
        if (lane == 0) sM = acc;                // total candidates
    }
    __syncthreads();
    int B = sB;
    int M = sM;
    int V = min(M, KCAP);
    if (bid == 0 && tid == 0) ctr[0] = V;

    // scatter: predicated stream over 132 segments of 512 (fill ~27%)
    for (int slot = bid * 1024 + tid; slot < NFB * 512; slot += MID_BLKS * 1024) {
        int seg = slot >> 9, off = slot & 511;
        if (off < scnt[seg]) {
            unsigned long long k = list[slot];
            int b = bucket_of((unsigned int)(k >> 32));
            if (b >= B) {
                int o = atomicAdd(&gfill[b], 1);
                int pos = chist[b] + o;
                if (pos < CAPG) gkeys[pos] = k;
            }
        }
    }
    __syncthreads();
    if (tid == 0) {
        __threadfence();                       // release scatter
        int old = atomicAdd(&ctr[1], 1);
        slast = (old == MID_BLKS - 1);
    }
    __syncthreads();
    if (!slast) return;
    if (tid == 0) __threadfence();             // acquire
    __syncthreads();

    int S = min((B > 0) ? chist[B - 1] : M, CAPG);
    for (int s = tid; s < S; s += 1024) {
        unsigned long long key = gkeys[s];
        unsigned int sb = (unsigned int)(key >> 32);
        int b = bucket_of(sb);
        int seg0 = chist[b];
        int segn = gfill[b];
        int within = 0;
        for (int t = 0; t < segn && seg0 + t < CAPG; ++t)
            within += (gkeys[seg0 + t] > key) ? 1 : 0;
        int r = seg0 + within;
        if (r < KCAP) {
            unsigned int a = 0xFFFFFFFFu - (unsigned int)(key & 0xFFFFFFFFull);
            sel_score[r] = __uint_as_float(sb);
            float pcx = priors[a*4+0], pcy = priors[a*4+1];
            float pw  = priors[a*4+2], ph  = priors[a*4+3];
            float l0 = loc[a*4+0], l1 = loc[a*4+1], l2 = loc[a*4+2], l3 = loc[a*4+3];
            // replicate reference op order exactly:
            float cx = pcx + (l0 * 0.1f) * pw;
            float cy = pcy + (l1 * 0.1f) * ph;
            float w  = pw * expf(l2 * 0.2f);
            float h2 = ph * expf(l3 * 0.2f);
            float x1 = cx - w * 0.5f;
            float y1 = cy - h2 * 0.5f;
            sel_box[r*4+0] = x1 * 1280.0f;
            sel_box[r*4+1] = y1 * 1280.0f;
            sel_box[r*4+2] = (x1 + w) * 1280.0f;
            sel_box[r*4+3] = (y1 + h2) * 1280.0f;
#pragma unroll
            for (int q = 0; q < 5; ++q) {
                float lx = land[a*10 + 2*q + 0];
                float ly = land[a*10 + 2*q + 1];
                sel_lm[r*10 + 2*q + 0] = (pcx + (lx * 0.1f) * pw) * 1280.0f;
                sel_lm[r*10 + 2*q + 1] = (pcy + (ly * 0.1f) * ph) * 1280.0f;
            }
        }
    }
}

// K3: sup matrix (16 rows per 1024-thread block, 63 blocks) + last-block
// sparse greedy scan + output write (release/acquire done-counter, r12).
__global__ __launch_bounds__(1024) void k_supscan(
        const float* __restrict__ sel_box,
        const float* __restrict__ sel_score,
        const float* __restrict__ sel_lm,
        int* __restrict__ ctr,
        unsigned long long* __restrict__ sup,
        float* __restrict__ out) {
#pragma clang fp contract(off)
    __shared__ unsigned long long sup_r[1024][16]; // [row][w ^ (row&15)]
    __shared__ unsigned long long mshare[16];
    __shared__ unsigned long long keep_final[16];
    __shared__ int slast;
    int tid = threadIdx.x;
    int wave = tid >> 6, lane = tid & 63;
    int V = min(ctr[0], KCAP);

    // ---- sup phase: wave handles row i ----
    {
        int i = blockIdx.x * 16 + wave;  // 0..1007
        if (i < KCAP) {
            bool irow = (i < V);
            float ax1 = 0.f, ay1 = 0.f, ax2 = 0.f, ay2 = 0.f, aarea = 0.f;
            if (irow) {
                ax1 = sel_box[i*4+0]; ay1 = sel_box[i*4+1];
                ax2 = sel_box[i*4+2]; ay2 = sel_box[i*4+3];
                aarea = (ax2 - ax1) * (ay2 - ay1);
            }
            for (int g = 0; g < 16; ++g) {
                int j = g * 64 + lane;
                bool pred = false;
                if (irow && j < V && j > i) {
                    float4 b = reinterpret_cast<const float4*>(sel_box)[j];
                    float barea = (b.z - b.x) * (b.w - b.y);
                    float ltx = fmaxf(ax1, b.x), lty = fmaxf(ay1, b.y);
                    float rbx = fminf(ax2, b.z), rby = fminf(ay2, b.w);
                    float wx = fmaxf(rbx - ltx, 0.0f);
                    float wy = fmaxf(rby - lty, 0.0f);
                    float inter = wx * wy;
                    float iou = inter / (aarea + barea - inter + 1e-12f);
                    pred = iou > NMS_THR;
                }
                unsigned long long mask = __ballot(pred);
                if (lane == 0) sup[i*16 + g] = mask;
            }
        }
    }
    __syncthreads();
    if (tid == 0) {
        __threadfence();                       // release sup
        int old = atomicAdd(&ctr[2], 1);
        slast = (old == SUP_BLKS - 1);
    }
    __syncthreads();
    if (!slast) return;
    if (tid == 0) __threadfence();             // acquire
    __syncthreads();

    // ---- scan phase (last block): stage sup via 16B loads, sparse resolve --
    {
        const ulonglong2* sup2 = reinterpret_cast<const ulonglong2*>(sup);
        for (int idx = tid; idx < KCAP * 8; idx += 1024) {
            ulonglong2 v = sup2[idx];
            int e0 = idx * 2;
            int r = e0 >> 4, w0 = e0 & 15;
            sup_r[r][w0 ^ (r & 15)] = v.x;
            sup_r[r][(w0 + 1) ^ (r & 15)] = v.y;
        }
    }
    if (tid < 24 * 16) { // zero rows 1000..1023
        int r = 1000 + (tid >> 4), w = tid & 15;
        sup_r[r][w ^ (r & 15)] = 0ull;
    }
    unsigned long long kw;
    {
        int lo = wave * 64;
        kw = (V >= lo + 64) ? ~0ull : (V <= lo ? 0ull : ((1ull << (V - lo)) - 1ull));
    }
    __syncthreads();

    for (int c = 0; c < 16; ++c) {
        if (wave == c) {
            unsigned long long drow = sup_r[c*64 + lane][c ^ (lane & 15)];
            unsigned int dlo = (unsigned int)drow;
            unsigned int dhi = (unsigned int)(drow >> 32);
            unsigned long long nz = __ballot(drow != 0ull);
            unsigned long long m = kw;
            unsigned long long todo = m & nz;
            while (todo) {
                int i = (int)__builtin_ctzll(todo);
                i = __builtin_amdgcn_readfirstlane(i);
                unsigned long long di =
                    (((unsigned long long)(unsigned int)__builtin_amdgcn_readlane(dhi, i)) << 32)
                  |  (unsigned long long)(unsigned int)__builtin_amdgcn_readlane(dlo, i);
                m &= ~di;            // di only holds j>i bits
                todo &= ~di;         // suppressed rows never processed
                todo &= todo - 1ull; // clear bit i
            }
            kw = m;
            if (lane == 0) mshare[c] = m;
        }
        __syncthreads();
        if (wave > c) {
            unsigned long long m = mshare[c];
            unsigned long long contrib = ((m >> lane) & 1ull)
                ? sup_r[c*64 + lane][wave ^ (lane & 15)] : 0ull;
            if (__ballot(contrib != 0ull) != 0ull) {
#pragma unroll
                for (int off = 1; off < 64; off <<= 1)
                    contrib |= shfl_xor_u64(contrib, off);
                kw &= ~contrib;
            }
        }
    }
    if (lane == 0) keep_final[wave] = kw;
    __syncthreads();

    // outputs: boxes [0,4000), scores [4000,5000), landms [5000,15000)
    for (int s = tid; s < KCAP; s += 1024) {
        bool kept = ((keep_final[s >> 6] >> (s & 63)) & 1ull) != 0ull;
        float4 b = make_float4(0.f, 0.f, 0.f, 0.f);
        float sc = 0.f;
        if (kept) {
            b  = reinterpret_cast<const float4*>(sel_box)[s];
            sc = sel_score[s];
        }
        reinterpret_cast<float4*>(out)[s] = b;
        out[4000 + s] = sc;
#pragma unroll
        for (int q = 0; q < 10; ++q)
            out[5000 + s*10 + q] = kept ? sel_lm[s*10 + q] : 0.f;
    }
}

extern "C" void kernel_launch(void* const* d_in, const int* in_sizes, int n_in,
                              void* d_out, int out_size, void* d_ws, size_t ws_size,
                              hipStream_t stream) {
    const float* loc    = (const float*)d_in[0];
    const float* conf   = (const float*)d_in[1];
    const float* land   = (const float*)d_in[2];
    const float* priors = (const float*)d_in[3];
    float* out = (float*)d_out;
    char* ws = (char*)d_ws;

    int* ctr                     = (int*)(ws + OFF_CTR);
    int* bcnt                    = (int*)(ws + OFF_BCNT);
    int* bhist                   = (int*)(ws + OFF_BHIST);
    int* gfill                   = (int*)(ws + OFF_FILL);
    unsigned long long* list     = (unsigned long long*)(ws + OFF_LIST);
    unsigned long long* gkeys    = (unsigned long long*)(ws + OFF_GKEYS);
    float* sel_score             = (float*)(ws + OFF_SCORE);
    float* sel_box               = (float*)(ws + OFF_BOX);
    float* sel_lm                = (float*)(ws + OFF_LM);
    unsigned long long* sup      = (unsigned long long*)(ws + OFF_SUP);

    k_front<<<NFB, 256, 0, stream>>>(conf, list, bhist, bcnt, gfill, ctr);
    k_midrank<<<MID_BLKS, 1024, 0, stream>>>(list, bhist, bcnt, gfill, gkeys,
                                             ctr, loc, land, priors,
                                             sel_score, sel_box, sel_lm);
    k_supscan<<<SUP_BLKS, 1024, 0, stream>>>(sel_box, sel_score, sel_lm, ctr,
                                             sup, out);
}

// Round 16
// 57.056 us; speedup vs baseline: 1.4017x; 1.1917x over previous
//
#include <hip/hip_runtime.h>
#include <stdint.h>

#define N_ANCH 67200
#define KCAP   1000
#define CONF_THR 0.7f
#define NMS_THR  0.4f

// score-bits histogram: scores in (0.7, 1.0] -> bits in (0x3F333333, 0x3F800000]
// span = 0x4CCCCD ulp; shift 10 -> 4917 live buckets; NBUCK = 5120 = 1024*5.
// (r14 lesson: keep buckets fine — avg segment ~4 keys for the exact rank.)
#define BUCK_BASE 0x3F333333u
#define BUCK_SHIFT 10
#define NBUCK 5120
#define CAPG 4096             // bucket-sorted key capacity (kept ~ 1010)

#define MID_BLKS 32
#define SUP_BLKS 63           // 63*16 = 1008 rows >= KCAP

// ---- workspace layout (bytes), ~801 KB total ----
#define OFF_CTR   0           // [0]=M, [1]=done_mid, [2]=done_sup
#define OFF_HIST  64          // +NBUCK*4 = 20480 -> 20544
#define OFF_FILL  20544       // +20480 -> 41024
#define OFF_LIST  41024       // +N_ANCH*8 = 537600 -> 578624
#define OFF_GKEYS 578624      // +CAPG*8 = 32768 -> 611392
#define OFF_SCORE 611392      // +4096 -> 615488
#define OFF_BOX   615488      // +16384 -> 631872 (16B aligned)
#define OFF_LM    631872      // +40960 -> 672832
#define OFF_SUP   672832      // +128000 -> 800832 (16B aligned)

__device__ inline unsigned long long shfl_xor_u64(unsigned long long v, int m) {
    unsigned int lo = (unsigned int)__shfl_xor((int)(v & 0xffffffffull), m, 64);
    unsigned int hi = (unsigned int)__shfl_xor((int)(v >> 32), m, 64);
    return ((unsigned long long)hi << 32) | lo;
}

__device__ inline int bucket_of(unsigned int sb) {
    return min((int)((sb - BUCK_BASE) >> BUCK_SHIFT), NBUCK - 1);
}

// findcut (largest B with suffix-count >= KCAP, else 0) + in-place suffix
// scan turning hist[] into sufx[] (descending segment starts). 1024 threads.
// readlane returns int -> widen through unsigned int (round-2 lesson).
__device__ inline void findcut_and_scan(int* sufx, int* swsum, int* sB,
                                        int tid, int lane, int wv) {
    if (tid < 64) {
        int acc = 0, B = 0;
        bool found = false;
        for (int t = 0; t < NBUCK / 64 && !found; ++t) {
            int base = NBUCK - 64 * (t + 1);
            int c = sufx[base + lane];
            int ssum = c;
#pragma unroll
            for (int off = 1; off < 64; off <<= 1)
                ssum += __shfl_xor(ssum, off, 64);
            if (acc + ssum >= KCAP) {
                for (int l = 63; l >= 0; --l) {
                    int cl = (int)__builtin_amdgcn_readlane((unsigned int)c, l);
                    if (acc + cl >= KCAP) { B = base + l; found = true; break; }
                    acc += cl;
                }
            } else {
                acc += ssum;
            }
        }
        if (lane == 0) *sB = found ? B : 0;
    }
    __syncthreads();
    int c[5];
#pragma unroll
    for (int k = 0; k < 5; ++k)
        c[k] = sufx[NBUCK - 1 - (tid * 5 + k)];
    int tsum = c[0] + c[1] + c[2] + c[3] + c[4];
    int inc = tsum;
#pragma unroll
    for (int off = 1; off < 64; off <<= 1) {
        int n = __shfl_up(inc, off, 64);
        if (lane >= off) inc += n;
    }
    if (lane == 63) swsum[wv] = inc;
    __syncthreads();
    if (tid < 16) {
        int v = swsum[tid];
        int s = v;
#pragma unroll
        for (int off = 1; off < 16; off <<= 1) {
            int n = __shfl_up(s, off, 64);
            if (tid >= off) s += n;
        }
        swsum[tid] = s - v;  // exclusive wave base
    }
    __syncthreads();
    int run = swsum[wv] + inc - tsum;  // exclusive prefix (reversed order)
#pragma unroll
    for (int k = 0; k < 5; ++k) {
        sufx[NBUCK - 1 - (tid * 5 + k)] = run;
        run += c[k];
    }
    __syncthreads();
}

// K0: zero counters + histogram + fill (rocclr fill is pathological: 40us).
__global__ __launch_bounds__(1024) void k_zero(int* __restrict__ ctr,
                                               int* __restrict__ hist,
                                               int* __restrict__ gfill) {
    int tid = threadIdx.x;
    if (tid < 16) ctr[tid] = 0;
    for (int t = tid; t < NBUCK; t += 1024) { hist[t] = 0; gfill[t] = 0; }
}

// K1: softmax, threshold, wave-aggregated dense compact + histogram.
// key = (score_bits<<32) | (0xFFFFFFFF - index): descending key order ==
// lax.top_k order (ties -> ascending index). List order nondeterministic;
// exact ranking downstream keeps outputs deterministic.
__global__ __launch_bounds__(256) void k_front(const float* __restrict__ conf,
                                               unsigned long long* __restrict__ list,
                                               int* __restrict__ hist,
                                               int* __restrict__ ctr) {
    int t = blockIdx.x * 256 + threadIdx.x;   // float4 index = 2 anchors
    int lane = threadIdx.x & 63;
    int a0 = t * 2;
    bool p0 = false, p1 = false;
    unsigned long long k0 = 0ull, k1 = 0ull;
    if (a0 < N_ANCH) {
        float4 c = reinterpret_cast<const float4*>(conf)[t];
        {
            float mx = fmaxf(c.x, c.y);
            float e0 = expf(c.x - mx), e1 = expf(c.y - mx);
            float s = e1 / (e0 + e1);
            if (s > CONF_THR) {
                p0 = true;
                k0 = ((unsigned long long)__float_as_uint(s) << 32)
                   | (unsigned int)(0xFFFFFFFFu - (unsigned int)a0);
            }
        }
        {
            float mx = fmaxf(c.z, c.w);
            float e0 = expf(c.z - mx), e1 = expf(c.w - mx);
            float s = e1 / (e0 + e1);
            if (s > CONF_THR) {
                p1 = true;
                k1 = ((unsigned long long)__float_as_uint(s) << 32)
                   | (unsigned int)(0xFFFFFFFFu - (unsigned int)(a0 + 1));
            }
        }
    }
    unsigned long long m0 = __ballot(p0);
    unsigned long long m1 = __ballot(p1);
    int n0 = (int)__popcll(m0), n1 = (int)__popcll(m1);
    int base = 0;
    if ((n0 + n1) > 0) {
        if (lane == 0) base = atomicAdd(&ctr[0], n0 + n1);
        base = __shfl(base, 0, 64);
        unsigned long long below = (1ull << lane) - 1ull;
        if (p0) {
            list[base + (int)__popcll(m0 & below)] = k0;
            atomicAdd(&hist[bucket_of((unsigned int)(k0 >> 32))], 1);
        }
        if (p1) {
            list[base + n0 + (int)__popcll(m1 & below)] = k1;
            atomicAdd(&hist[bucket_of((unsigned int)(k1 >> 32))], 1);
        }
    }
}

// K2: parallel filter-scatter + last-block rank+decode. Each of MID_BLKS
// blocks computes findcut+sufx from hist, scatters its slice of kept keys
// (b >= B) into bucket-sorted gkeys. The LAST block to finish (device-scope
// done counter + threadfence release/acquire, validated r11/r12) ranks &
// decodes all S keys, reusing its LDS sufx. Exact rank -> deterministic.
__global__ __launch_bounds__(1024) void k_midrank(
        const unsigned long long* __restrict__ list,
        const int* __restrict__ hist,
        int* __restrict__ gfill,
        unsigned long long* __restrict__ gkeys,
        int* __restrict__ ctr,
        const float* __restrict__ loc,
        const float* __restrict__ land,
        const float* __restrict__ priors,
        float* __restrict__ sel_score,
        float* __restrict__ sel_box,
        float* __restrict__ sel_lm) {
#pragma clang fp contract(off)
    __shared__ int sufx[NBUCK];
    __shared__ int swsum[16];
    __shared__ int sB;
    __shared__ int slast;
    int tid = threadIdx.x, lane = tid & 63, wv = tid >> 6;
    for (int t = tid; t < NBUCK; t += 1024) sufx[t] = hist[t];
    __syncthreads();
    findcut_and_scan(sufx, swsum, &sB, tid, lane, wv);
    int B = sB;
    int M = min(ctr[0], N_ANCH);

    for (int p = blockIdx.x * 1024 + tid; p < M; p += MID_BLKS * 1024) {
        unsigned long long k = list[p];
        int b = bucket_of((unsigned int)(k >> 32));
        if (b >= B) {
            int off = atomicAdd(&gfill[b], 1);
            int slot = sufx[b] + off;
            if (slot < CAPG) gkeys[slot] = k;
        }
    }
    __syncthreads();               // all block stores issued+drained
    if (tid == 0) {
        __threadfence();           // release: make scatter visible device-wide
        int old = atomicAdd(&ctr[1], 1);
        slast = (old == MID_BLKS - 1);
    }
    __syncthreads();
    if (!slast) return;
    if (tid == 0) __threadfence(); // acquire: invalidate stale cache
    __syncthreads();

    int S = min((B > 0) ? sufx[B - 1] : M, CAPG);
    for (int s = tid; s < S; s += 1024) {
        unsigned long long key = gkeys[s];
        unsigned int sb = (unsigned int)(key >> 32);
        int b = bucket_of(sb);
        int seg0 = sufx[b];
        int segn = gfill[b];
        int within = 0;
        for (int t = 0; t < segn && seg0 + t < CAPG; ++t)
            within += (gkeys[seg0 + t] > key) ? 1 : 0;
        int r = seg0 + within;
        if (r < KCAP) {
            unsigned int a = 0xFFFFFFFFu - (unsigned int)(key & 0xFFFFFFFFull);
            sel_score[r] = __uint_as_float(sb);
            float pcx = priors[a*4+0], pcy = priors[a*4+1];
            float pw  = priors[a*4+2], ph  = priors[a*4+3];
            float l0 = loc[a*4+0], l1 = loc[a*4+1], l2 = loc[a*4+2], l3 = loc[a*4+3];
            // replicate reference op order exactly:
            float cx = pcx + (l0 * 0.1f) * pw;
            float cy = pcy + (l1 * 0.1f) * ph;
            float w  = pw * expf(l2 * 0.2f);
            float h2 = ph * expf(l3 * 0.2f);
            float x1 = cx - w * 0.5f;
            float y1 = cy - h2 * 0.5f;
            sel_box[r*4+0] = x1 * 1280.0f;
            sel_box[r*4+1] = y1 * 1280.0f;
            sel_box[r*4+2] = (x1 + w) * 1280.0f;
            sel_box[r*4+3] = (y1 + h2) * 1280.0f;
#pragma unroll
            for (int q = 0; q < 5; ++q) {
                float lx = land[a*10 + 2*q + 0];
                float ly = land[a*10 + 2*q + 1];
                sel_lm[r*10 + 2*q + 0] = (pcx + (lx * 0.1f) * pw) * 1280.0f;
                sel_lm[r*10 + 2*q + 1] = (pcy + (ly * 0.1f) * ph) * 1280.0f;
            }
        }
    }
}

// K3: sup matrix (16 rows per 1024-thread block, 63 blocks) + last-block
// sparse greedy scan + output write. Release/acquire done-counter (r12);
// ulonglong2 sup staging (validated r13/r14).
__global__ __launch_bounds__(1024) void k_supscan(
        const float* __restrict__ sel_box,
        const float* __restrict__ sel_score,
        const float* __restrict__ sel_lm,
        int* __restrict__ ctr,
        unsigned long long* __restrict__ sup,
        float* __restrict__ out) {
#pragma clang fp contract(off)
    __shared__ unsigned long long sup_r[1024][16]; // [row][w ^ (row&15)]
    __shared__ unsigned long long mshare[16];
    __shared__ unsigned long long keep_final[16];
    __shared__ int slast;
    int tid = threadIdx.x;
    int wave = tid >> 6, lane = tid & 63;
    int V = min(ctr[0], KCAP);

    // ---- sup phase: wave handles row i ----
    {
        int i = blockIdx.x * 16 + wave;  // 0..1007
        if (i < KCAP) {
            bool irow = (i < V);
            float ax1 = 0.f, ay1 = 0.f, ax2 = 0.f, ay2 = 0.f, aarea = 0.f;
            if (irow) {
                ax1 = sel_box[i*4+0]; ay1 = sel_box[i*4+1];
                ax2 = sel_box[i*4+2]; ay2 = sel_box[i*4+3];
                aarea = (ax2 - ax1) * (ay2 - ay1);
            }
            for (int g = 0; g < 16; ++g) {
                int j = g * 64 + lane;
                bool pred = false;
                if (irow && j < V && j > i) {
                    float4 b = reinterpret_cast<const float4*>(sel_box)[j];
                    float barea = (b.z - b.x) * (b.w - b.y);
                    float ltx = fmaxf(ax1, b.x), lty = fmaxf(ay1, b.y);
                    float rbx = fminf(ax2, b.z), rby = fminf(ay2, b.w);
                    float wx = fmaxf(rbx - ltx, 0.0f);
                    float wy = fmaxf(rby - lty, 0.0f);
                    float inter = wx * wy;
                    float iou = inter / (aarea + barea - inter + 1e-12f);
                    pred = iou > NMS_THR;
                }
                unsigned long long mask = __ballot(pred);
                if (lane == 0) sup[i*16 + g] = mask;
            }
        }
    }
    __syncthreads();               // all block stores drained
    if (tid == 0) {
        __threadfence();           // release
        int old = atomicAdd(&ctr[2], 1);
        slast = (old == SUP_BLKS - 1);
    }
    __syncthreads();
    if (!slast) return;
    if (tid == 0) __threadfence(); // acquire
    __syncthreads();

    // ---- scan phase (last block): stage sup via 16B loads, sparse resolve --
    {
        const ulonglong2* sup2 = reinterpret_cast<const ulonglong2*>(sup);
        for (int idx = tid; idx < KCAP * 8; idx += 1024) {
            ulonglong2 v = sup2[idx];
            int e0 = idx * 2;
            int r = e0 >> 4, w0 = e0 & 15;
            sup_r[r][w0 ^ (r & 15)] = v.x;
            sup_r[r][(w0 + 1) ^ (r & 15)] = v.y;
        }
    }
    if (tid < 24 * 16) { // zero rows 1000..1023
        int r = 1000 + (tid >> 4), w = tid & 15;
        sup_r[r][w ^ (r & 15)] = 0ull;
    }
    unsigned long long kw;
    {
        int lo = wave * 64;
        kw = (V >= lo + 64) ? ~0ull : (V <= lo ? 0ull : ((1ull << (V - lo)) - 1ull));
    }
    __syncthreads();

    for (int c = 0; c < 16; ++c) {
        if (wave == c) {
            unsigned long long drow = sup_r[c*64 + lane][c ^ (lane & 15)];
            unsigned int dlo = (unsigned int)drow;
            unsigned int dhi = (unsigned int)(drow >> 32);
            unsigned long long nz = __ballot(drow != 0ull);
            unsigned long long m = kw;
            unsigned long long todo = m & nz;
            while (todo) {
                int i = (int)__builtin_ctzll(todo);
                i = __builtin_amdgcn_readfirstlane(i);
                unsigned long long di =
                    (((unsigned long long)(unsigned int)__builtin_amdgcn_readlane(dhi, i)) << 32)
                  |  (unsigned long long)(unsigned int)__builtin_amdgcn_readlane(dlo, i);
                m &= ~di;            // di only holds j>i bits
                todo &= ~di;         // suppressed rows never processed
                todo &= todo - 1ull; // clear bit i
            }
            kw = m;
            if (lane == 0) mshare[c] = m;
        }
        __syncthreads();
        if (wave > c) {
            unsigned long long m = mshare[c];
            unsigned long long contrib = ((m >> lane) & 1ull)
                ? sup_r[c*64 + lane][wave ^ (lane & 15)] : 0ull;
            if (__ballot(contrib != 0ull) != 0ull) {
#pragma unroll
                for (int off = 1; off < 64; off <<= 1)
                    contrib |= shfl_xor_u64(contrib, off);
                kw &= ~contrib;
            }
        }
    }
    if (lane == 0) keep_final[wave] = kw;
    __syncthreads();

    // outputs: boxes [0,4000), scores [4000,5000), landms [5000,15000)
    for (int s = tid; s < KCAP; s += 1024) {
        bool kept = ((keep_final[s >> 6] >> (s & 63)) & 1ull) != 0ull;
        float4 b = make_float4(0.f, 0.f, 0.f, 0.f);
        float sc = 0.f;
        if (kept) {
            b  = reinterpret_cast<const float4*>(sel_box)[s];
            sc = sel_score[s];
        }
        reinterpret_cast<float4*>(out)[s] = b;
        out[4000 + s] = sc;
#pragma unroll
        for (int q = 0; q < 10; ++q)
            out[5000 + s*10 + q] = kept ? sel_lm[s*10 + q] : 0.f;
    }
}

extern "C" void kernel_launch(void* const* d_in, const int* in_sizes, int n_in,
                              void* d_out, int out_size, void* d_ws, size_t ws_size,
                              hipStream_t stream) {
    const float* loc    = (const float*)d_in[0];
    const float* conf   = (const float*)d_in[1];
    const float* land   = (const float*)d_in[2];
    const float* priors = (const float*)d_in[3];
    float* out = (float*)d_out;
    char* ws = (char*)d_ws;

    int* ctr                     = (int*)(ws + OFF_CTR);
    int* hist                    = (int*)(ws + OFF_HIST);
    int* gfill                   = (int*)(ws + OFF_FILL);
    unsigned long long* list     = (unsigned long long*)(ws + OFF_LIST);
    unsigned long long* gkeys    = (unsigned long long*)(ws + OFF_GKEYS);
    float* sel_score             = (float*)(ws + OFF_SCORE);
    float* sel_box               = (float*)(ws + OFF_BOX);
    float* sel_lm                = (float*)(ws + OFF_LM);
    unsigned long long* sup      = (unsigned long long*)(ws + OFF_SUP);

    int nfb = (N_ANCH / 2 + 255) / 256; // 132
    k_zero<<<1, 1024, 0, stream>>>(ctr, hist, gfill);
    k_front<<<nfb, 256, 0, stream>>>(conf, list, hist, ctr);
    k_midrank<<<MID_BLKS, 1024, 0, stream>>>(list, hist, gfill, gkeys, ctr,
                                             loc, land, priors,
                                             sel_score, sel_box, sel_lm);
    k_supscan<<<SUP_BLKS, 1024, 0, stream>>>(sel_box, sel_score, sel_lm, ctr,
                                             sup, out);
}